// Round 1
// baseline (3079.220 us; speedup 1.0000x reference)
//
#include <hip/hip_runtime.h>

#define HW    128
#define NPIX  16384      // 128*128
#define CDIM  256
#define DLOI  128
#define LROWS 40000      // B*L = 8*5000
#define DFC   1024
#define KIN   1032       // DLOI*8 + 8

// ---------------- conv1x1: x[b][h][w][d] = sum_c feature[b][c][h][w] * W[d][c] + bias[d]
__global__ __launch_bounds__(256) void conv1x1_kernel(
    const float* __restrict__ feature, const float* __restrict__ Wfc,
    const float* __restrict__ bfc, float* __restrict__ x) {
  __shared__ float Wl[64][128];              // [c-chunk][d], 32 KiB
  const int tid = threadIdx.x;
  const int b = blockIdx.y;
  const int pixbase = blockIdx.x * 256;
  const int dh = tid & 3;                    // d-quarter: 32 d's
  const int pp = tid >> 2;                   // 0..63
  const float* fb = feature + (size_t)b * CDIM * NPIX + pixbase;

  float acc[4][32];
#pragma unroll
  for (int j = 0; j < 4; ++j)
#pragma unroll
    for (int dd = 0; dd < 32; ++dd) acc[j][dd] = 0.f;

  for (int cc = 0; cc < CDIM; cc += 64) {
    __syncthreads();
    for (int e = tid; e < 64 * 128; e += 256) {
      int c = e >> 7, d = e & 127;
      Wl[c][d] = Wfc[d * CDIM + cc + c];
    }
    __syncthreads();
    for (int c = 0; c < 64; ++c) {
      float f0 = fb[(size_t)(cc + c) * NPIX + pp];
      float f1 = fb[(size_t)(cc + c) * NPIX + pp + 64];
      float f2 = fb[(size_t)(cc + c) * NPIX + pp + 128];
      float f3 = fb[(size_t)(cc + c) * NPIX + pp + 192];
      const float* wrow = &Wl[c][dh * 32];
#pragma unroll
      for (int dd = 0; dd < 32; ++dd) {
        float w = wrow[dd];
        acc[0][dd] += f0 * w;
        acc[1][dd] += f1 * w;
        acc[2][dd] += f2 * w;
        acc[3][dd] += f3 * w;
      }
    }
  }
#pragma unroll
  for (int j = 0; j < 4; ++j) {
    size_t pix = (size_t)pixbase + pp + j * 64;
    float* xo = x + ((size_t)b * NPIX + pix) * DLOI + dh * 32;
#pragma unroll
    for (int dd = 0; dd < 32; ++dd)
      xo[dd] = acc[j][dd] + bfc[dh * 32 + dd];
  }
}

// ---------------- sampling + bilinear + maxpool(4) + concat feat -> z[40000][1032]
__global__ __launch_bounds__(256) void sample_kernel(
    const float* __restrict__ x, const float* __restrict__ p,
    const float* __restrict__ feat, float* __restrict__ z) {
  const int tid = threadIdx.x;
  const int t = tid & 31;                    // point index 0..31
  const int ll = tid >> 5;                   // line-in-block 0..7
  const int b = blockIdx.y;
  const int row = b * 5000 + blockIdx.x * 8 + ll;

  const float4 pe = *(const float4*)&p[(size_t)row * 4]; // p0x p0y p1x p1y
  const float lam = (float)t * (1.0f / 31.0f);
  const float px = pe.x * lam + pe.z * (1.f - lam) - 0.5f;
  const float py = pe.y * lam + pe.w * (1.f - lam) - 0.5f;
  const float px0 = fminf(fmaxf(floorf(px), 0.f), 127.f);
  const float py0 = fminf(fmaxf(floorf(py), 0.f), 127.f);
  const float px1 = fminf(px0 + 1.f, 127.f);
  const float py1 = fminf(py0 + 1.f, 127.f);
  const int ix0 = (int)px0, iy0 = (int)py0, ix1 = (int)px1, iy1 = (int)py1;
  const float w00 = (px1 - px) * (py1 - py);
  const float w10 = (px - px0) * (py1 - py);
  const float w01 = (px1 - px) * (py - py0);
  const float w11 = (px - px0) * (py - py0);

  const size_t bb = (size_t)b * NPIX;
  const float* r00 = x + (bb + ix0 * HW + iy0) * DLOI;
  const float* r10 = x + (bb + ix1 * HW + iy0) * DLOI;
  const float* r01 = x + (bb + ix0 * HW + iy1) * DLOI;
  const float* r11 = x + (bb + ix1 * HW + iy1) * DLOI;
  float* zr = z + (size_t)row * KIN;
  const int q = t >> 2;

  for (int c4 = 0; c4 < 32; ++c4) {
    float4 a  = *(const float4*)&r00[c4 * 4];
    float4 bq = *(const float4*)&r10[c4 * 4];
    float4 cq = *(const float4*)&r01[c4 * 4];
    float4 dq = *(const float4*)&r11[c4 * 4];
    float v[4];
    v[0] = w00 * a.x + w10 * bq.x + w01 * cq.x + w11 * dq.x;
    v[1] = w00 * a.y + w10 * bq.y + w01 * cq.y + w11 * dq.y;
    v[2] = w00 * a.z + w10 * bq.z + w01 * cq.z + w11 * dq.z;
    v[3] = w00 * a.w + w10 * bq.w + w01 * cq.w + w11 * dq.w;
#pragma unroll
    for (int ci = 0; ci < 4; ++ci) {
      float m = v[ci];
      m = fmaxf(m, __shfl_xor(m, 1));
      m = fmaxf(m, __shfl_xor(m, 2));
      if ((t & 3) == 0) zr[(c4 * 4 + ci) * 8 + q] = m;
    }
  }
  if (t < 8) zr[1024 + t] = feat[(size_t)row * 8 + t];
}

// ---------------- fp32 GEMM: C[M][1024] = relu(A[M][K] @ B[K][1024] + bias)
__global__ __launch_bounds__(256) void gemm_kernel(
    const float* __restrict__ A, const float* __restrict__ B,
    const float* __restrict__ bias, float* __restrict__ C,
    int M, int K, int lda, int relu) {
  __shared__ float As[8][128];
  __shared__ float Bs[8][128];
  const int tid = threadIdx.x;
  const int tx = tid & 15, ty = tid >> 4;
  const int m0 = blockIdx.y * 128, n0 = blockIdx.x * 128;

  float acc[8][8];
#pragma unroll
  for (int i = 0; i < 8; ++i)
#pragma unroll
    for (int j = 0; j < 8; ++j) acc[i][j] = 0.f;

  const int ar = tid >> 1;
  const int aj = (tid & 1) * 4;
  int arow = m0 + ar; if (arow >= M) arow = M - 1;
  const int bk = tid >> 5, bc = (tid & 31) * 4;

  for (int kk = 0; kk < K; kk += 8) {
    float4 av = *(const float4*)&A[(size_t)arow * lda + kk + aj];
    float4 bv = *(const float4*)&B[(size_t)(kk + bk) * DFC + n0 + bc];
    __syncthreads();
    As[aj + 0][ar] = av.x; As[aj + 1][ar] = av.y;
    As[aj + 2][ar] = av.z; As[aj + 3][ar] = av.w;
    *(float4*)&Bs[bk][bc] = bv;
    __syncthreads();
#pragma unroll
    for (int k = 0; k < 8; ++k) {
      float a[8], bb[8];
      *(float4*)&a[0]  = *(const float4*)&As[k][ty * 8];
      *(float4*)&a[4]  = *(const float4*)&As[k][ty * 8 + 4];
      *(float4*)&bb[0] = *(const float4*)&Bs[k][tx * 8];
      *(float4*)&bb[4] = *(const float4*)&Bs[k][tx * 8 + 4];
#pragma unroll
      for (int i = 0; i < 8; ++i)
#pragma unroll
        for (int j = 0; j < 8; ++j) acc[i][j] += a[i] * bb[j];
    }
  }
#pragma unroll
  for (int i = 0; i < 8; ++i) {
    int m = m0 + ty * 8 + i;
    if (m >= M) continue;
    float* crow = C + (size_t)m * DFC + n0 + tx * 8;
    float4 v0, v1;
    v0.x = acc[i][0] + bias[n0 + tx * 8 + 0];
    v0.y = acc[i][1] + bias[n0 + tx * 8 + 1];
    v0.z = acc[i][2] + bias[n0 + tx * 8 + 2];
    v0.w = acc[i][3] + bias[n0 + tx * 8 + 3];
    v1.x = acc[i][4] + bias[n0 + tx * 8 + 4];
    v1.y = acc[i][5] + bias[n0 + tx * 8 + 5];
    v1.z = acc[i][6] + bias[n0 + tx * 8 + 6];
    v1.w = acc[i][7] + bias[n0 + tx * 8 + 7];
    if (relu) {
      v0.x = fmaxf(v0.x, 0.f); v0.y = fmaxf(v0.y, 0.f);
      v0.z = fmaxf(v0.z, 0.f); v0.w = fmaxf(v0.w, 0.f);
      v1.x = fmaxf(v1.x, 0.f); v1.y = fmaxf(v1.y, 0.f);
      v1.z = fmaxf(v1.z, 0.f); v1.w = fmaxf(v1.w, 0.f);
    }
    *(float4*)&crow[0] = v0;
    *(float4*)&crow[4] = v1;
  }
}

// ---------------- fc3: out[m] = h2[m] . W3 + b3
__global__ __launch_bounds__(256) void fc3_kernel(
    const float* __restrict__ H, const float* __restrict__ W3,
    const float* __restrict__ b3, float* __restrict__ out, int M) {
  const int lane = threadIdx.x & 63;
  const int w = threadIdx.x >> 6;
  const int row = blockIdx.x * 4 + w;
  if (row >= M) return;
  const float* hr = H + (size_t)row * DFC;
  float s = 0.f;
#pragma unroll
  for (int k = 0; k < 4; ++k) {
    int j = (lane + k * 64) * 4;
    float4 hv = *(const float4*)&hr[j];
    float4 wv = *(const float4*)&W3[j];
    s += hv.x * wv.x + hv.y * wv.y + hv.z * wv.z + hv.w * wv.w;
  }
  for (int off = 32; off; off >>= 1) s += __shfl_xor(s, off);
  if (lane == 0) out[row] = s + b3[0];
}

extern "C" void kernel_launch(void* const* d_in, const int* in_sizes, int n_in,
                              void* d_out, int out_size, void* d_ws, size_t ws_size,
                              hipStream_t stream) {
  const float* feature = (const float*)d_in[0];
  const float* p       = (const float*)d_in[1];
  const float* feat    = (const float*)d_in[2];
  const float* W_fc1   = (const float*)d_in[3];
  const float* b_fc1   = (const float*)d_in[4];
  const float* W1      = (const float*)d_in[5];
  const float* b1      = (const float*)d_in[6];
  const float* W2      = (const float*)d_in[7];
  const float* b2      = (const float*)d_in[8];
  const float* W3      = (const float*)d_in[9];
  const float* b3      = (const float*)d_in[10];
  float* out = (float*)d_out;

  char* ws = (char*)d_ws;
  const size_t x_off  = 0;                       // 8*16384*128*4   = 67,108,864
  const size_t z_off  = x_off + 67108864ULL;     // 40000*1032*4    = 165,120,000
  const size_t h1_off = z_off + 165120000ULL;    // 40000*1024*4    = 163,840,000
  float* x  = (float*)(ws + x_off);
  float* z  = (float*)(ws + z_off);
  float* h1 = (float*)(ws + h1_off);
  float* h2 = z;  // z dead after fc1 -> alias

  hipLaunchKernelGGL(conv1x1_kernel, dim3(64, 8), dim3(256), 0, stream,
                     feature, W_fc1, b_fc1, x);
  hipLaunchKernelGGL(sample_kernel, dim3(625, 8), dim3(256), 0, stream,
                     x, p, feat, z);
  hipLaunchKernelGGL(gemm_kernel, dim3(8, 313), dim3(256), 0, stream,
                     z, W1, b1, h1, LROWS, KIN, KIN, 1);
  hipLaunchKernelGGL(gemm_kernel, dim3(8, 313), dim3(256), 0, stream,
                     h1, W2, b2, h2, LROWS, DFC, DFC, 1);
  hipLaunchKernelGGL(fc3_kernel, dim3(10000), dim3(256), 0, stream,
                     h2, W3, b3, out, LROWS);
}

// Round 2
// 740.714 us; speedup vs baseline: 4.1571x; 4.1571x over previous
//
#include <hip/hip_runtime.h>

typedef _Float16 f16;
typedef f16 f16x8 __attribute__((ext_vector_type(8)));
typedef float f32x4 __attribute__((ext_vector_type(4)));

#define HW    128
#define NPIX  16384      // 128*128
#define CDIM  256
#define DLOI  128
#define LROWS 40000      // B*L
#define DFC   1024
#define KP1   1088       // fc1 K (1032) padded to 17*64

// ---------------- conv1x1: x[b][pix][d] (fp16) = sum_c feature[b][c][pix] * W[d][c] + bias
__global__ __launch_bounds__(256) void conv1x1_kernel(
    const float* __restrict__ feature, const float* __restrict__ Wfc,
    const float* __restrict__ bfc, f16* __restrict__ x) {
  __shared__ float Wl[64][128];
  const int tid = threadIdx.x;
  const int b = blockIdx.y;
  const int pixbase = blockIdx.x * 256;
  const int dh = tid & 3;
  const int pp = tid >> 2;
  const float* fb = feature + (size_t)b * CDIM * NPIX + pixbase;

  float acc[4][32];
#pragma unroll
  for (int j = 0; j < 4; ++j)
#pragma unroll
    for (int dd = 0; dd < 32; ++dd) acc[j][dd] = 0.f;

  for (int cc = 0; cc < CDIM; cc += 64) {
    __syncthreads();
    for (int e = tid; e < 64 * 128; e += 256) {
      int c = e >> 7, d = e & 127;
      Wl[c][d] = Wfc[d * CDIM + cc + c];
    }
    __syncthreads();
    for (int c = 0; c < 64; ++c) {
      float f0 = fb[(size_t)(cc + c) * NPIX + pp];
      float f1 = fb[(size_t)(cc + c) * NPIX + pp + 64];
      float f2 = fb[(size_t)(cc + c) * NPIX + pp + 128];
      float f3 = fb[(size_t)(cc + c) * NPIX + pp + 192];
      const float* wrow = &Wl[c][dh * 32];
#pragma unroll
      for (int dd = 0; dd < 32; ++dd) {
        float w = wrow[dd];
        acc[0][dd] += f0 * w; acc[1][dd] += f1 * w;
        acc[2][dd] += f2 * w; acc[3][dd] += f3 * w;
      }
    }
  }
  float bv[32];
#pragma unroll
  for (int dd = 0; dd < 32; ++dd) bv[dd] = bfc[dh * 32 + dd];
#pragma unroll
  for (int j = 0; j < 4; ++j) {
    size_t pix = (size_t)pixbase + pp + j * 64;
    f16* xo = x + ((size_t)b * NPIX + pix) * DLOI + dh * 32;
#pragma unroll
    for (int dd = 0; dd < 32; ++dd)
      xo[dd] = (f16)(acc[j][dd] + bv[dd]);
  }
}

// ---------------- sampling + bilinear + maxpool(4) + concat -> z[40000][1088] fp16
__global__ __launch_bounds__(256) void sample_kernel(
    const f16* __restrict__ x, const float* __restrict__ p,
    const float* __restrict__ feat, f16* __restrict__ z) {
  const int tid = threadIdx.x;
  const int t = tid & 31;
  const int ll = tid >> 5;
  const int bid = blockIdx.x;          // 0..4999
  const int b = bid & 7;               // batch -> XCD pin (round-robin dispatch)
  const int grp = bid >> 3;            // 0..624
  const int row = b * 5000 + grp * 8 + ll;

  const float4 pe = *(const float4*)&p[(size_t)row * 4];
  const float lam = (float)t * (1.0f / 31.0f);
  const float px = pe.x * lam + pe.z * (1.f - lam) - 0.5f;
  const float py = pe.y * lam + pe.w * (1.f - lam) - 0.5f;
  const float px0 = fminf(fmaxf(floorf(px), 0.f), 127.f);
  const float py0 = fminf(fmaxf(floorf(py), 0.f), 127.f);
  const float px1 = fminf(px0 + 1.f, 127.f);
  const float py1 = fminf(py0 + 1.f, 127.f);
  const int ix0 = (int)px0, iy0 = (int)py0, ix1 = (int)px1, iy1 = (int)py1;
  const float w00 = (px1 - px) * (py1 - py);
  const float w10 = (px - px0) * (py1 - py);
  const float w01 = (px1 - px) * (py - py0);
  const float w11 = (px - px0) * (py - py0);

  const size_t bb = (size_t)b * NPIX;
  const f16* r00 = x + (bb + ix0 * HW + iy0) * DLOI;
  const f16* r10 = x + (bb + ix1 * HW + iy0) * DLOI;
  const f16* r01 = x + (bb + ix0 * HW + iy1) * DLOI;
  const f16* r11 = x + (bb + ix1 * HW + iy1) * DLOI;
  f16* zr = z + (size_t)row * KP1;
  const int q = t >> 2;

  for (int c8 = 0; c8 < 16; ++c8) {
    f16x8 a  = *(const f16x8*)&r00[c8 * 8];
    f16x8 bq = *(const f16x8*)&r10[c8 * 8];
    f16x8 cq = *(const f16x8*)&r01[c8 * 8];
    f16x8 dq = *(const f16x8*)&r11[c8 * 8];
#pragma unroll
    for (int ci = 0; ci < 8; ++ci) {
      float m = w00 * (float)a[ci] + w10 * (float)bq[ci] +
                w01 * (float)cq[ci] + w11 * (float)dq[ci];
      m = fmaxf(m, __shfl_xor(m, 1));
      m = fmaxf(m, __shfl_xor(m, 2));
      if ((t & 3) == 0) zr[(c8 * 8 + ci) * 8 + q] = (f16)m;
    }
  }
  if (t < 8) zr[1024 + t] = (f16)feat[(size_t)row * 8 + t];
  if (t < 28) *(unsigned int*)((char*)zr + 2064 + t * 4) = 0u;  // pad cols 1032..1087
}

// ---------------- weight transpose + fp16 + K-pad: Wt[n][k] = (f16)W[k][n]
__global__ __launch_bounds__(256) void wtrans_kernel(
    const float* __restrict__ W, f16* __restrict__ Wt, int K, int ldt) {
  __shared__ float t[32][33];
  const int tx = threadIdx.x & 31, ty = threadIdx.x >> 5;
#pragma unroll
  for (int i = 0; i < 4; ++i) {
    int k = blockIdx.y * 32 + ty + i * 8;
    int n = blockIdx.x * 32 + tx;
    t[ty + i * 8][tx] = (k < K) ? W[(size_t)k * DFC + n] : 0.f;
  }
  __syncthreads();
#pragma unroll
  for (int i = 0; i < 4; ++i) {
    int n = blockIdx.x * 32 + ty + i * 8;
    int k = blockIdx.y * 32 + tx;
    Wt[(size_t)n * ldt + k] = (f16)t[tx][ty + i * 8];
  }
}

// ---------------- fp16 MFMA GEMM: C[M][1024] = relu_f16(A[M][lda] @ Bt[1024][lda]^T + bias)
// 128x128 tile, BK=64, global_load_lds + XOR-swizzled LDS (slot ^ (row&7))
__global__ __launch_bounds__(256) void gemm_f16(
    const f16* __restrict__ A, const f16* __restrict__ Bt,
    const float* __restrict__ bias, f16* __restrict__ C,
    int M, int ksteps, int lda) {
  __shared__ f16 As[128 * 64];
  __shared__ f16 Bs[128 * 64];
  const int tid = threadIdx.x;
  const int l = tid & 63;
  const int w = tid >> 6;

  // bijective XCD swizzle: consecutive bids -> different XCDs; each XCD gets
  // a contiguous chunk of m-tiles with all 8 n-tiles (A panel L2-resident).
  const int nwg = gridDim.x;            // 2504 (313 m-tiles x 8 n-tiles)
  const int s = (blockIdx.x & 7) * (nwg >> 3) + (blockIdx.x >> 3);
  const int m0 = (s >> 3) * 128;
  const int n0 = (s & 7) * 128;

  const int wr = (w >> 1) * 64, wc = (w & 1) * 64;
  const int srow = w * 8 + (l >> 3);    // staging row within 32-row group
  const int slot = l & 7;

  f32x4 acc[4][4] = {};

  for (int kt = 0; kt < ksteps; ++kt) {
    const int kb = kt * 64;
    __syncthreads();  // LDS free from previous compute
#pragma unroll
    for (int c = 0; c < 4; ++c) {
      int row = c * 32 + srow;
      int arow = m0 + row; if (arow >= M) arow = M - 1;
      const f16* g = A + (size_t)arow * lda + kb + ((slot ^ (row & 7)) * 8);
      __builtin_amdgcn_global_load_lds(
          (const __attribute__((address_space(1))) void*)g,
          (__attribute__((address_space(3))) void*)(As + row * 64 + slot * 8),
          16, 0, 0);
    }
#pragma unroll
    for (int c = 0; c < 4; ++c) {
      int row = c * 32 + srow;
      const f16* g = Bt + (size_t)(n0 + row) * lda + kb + ((slot ^ (row & 7)) * 8);
      __builtin_amdgcn_global_load_lds(
          (const __attribute__((address_space(1))) void*)g,
          (__attribute__((address_space(3))) void*)(Bs + row * 64 + slot * 8),
          16, 0, 0);
    }
    __syncthreads();  // vmcnt(0) drain + barrier: tiles ready

    const int lrow = l & 15;
    const int g4 = l >> 4;
#pragma unroll
    for (int kh = 0; kh < 2; ++kh) {
      f16x8 af[4], bf[4];
#pragma unroll
      for (int m = 0; m < 4; ++m) {
        int row = wr + m * 16 + lrow;
        int sl = (g4 + 4 * kh) ^ (row & 7);
        af[m] = *(const f16x8*)(As + row * 64 + sl * 8);
      }
#pragma unroll
      for (int n = 0; n < 4; ++n) {
        int row = wc + n * 16 + lrow;
        int sl = (g4 + 4 * kh) ^ (row & 7);
        bf[n] = *(const f16x8*)(Bs + row * 64 + sl * 8);
      }
#pragma unroll
      for (int m = 0; m < 4; ++m)
#pragma unroll
        for (int n = 0; n < 4; ++n)
          acc[m][n] = __builtin_amdgcn_mfma_f32_16x16x32_f16(af[m], bf[n], acc[m][n], 0, 0, 0);
    }
  }

  // epilogue: C/D layout col=l&15, row=(l>>4)*4+reg
  const int ocol0 = n0 + wc + (l & 15);
  const int orow0 = m0 + wr + (l >> 4) * 4;
#pragma unroll
  for (int m = 0; m < 4; ++m) {
#pragma unroll
    for (int r = 0; r < 4; ++r) {
      int orow = orow0 + m * 16 + r;
      if (orow >= M) continue;
      f16* crow = C + (size_t)orow * DFC;
#pragma unroll
      for (int n = 0; n < 4; ++n) {
        int col = ocol0 + n * 16;
        float v = acc[m][n][r] + bias[col];
        crow[col] = (f16)fmaxf(v, 0.f);
      }
    }
  }
}

// ---------------- fc3: out[m] = h2[m] . W3 + b3   (h2 fp16, W3 fp32)
__global__ __launch_bounds__(256) void fc3_kernel(
    const f16* __restrict__ H, const float* __restrict__ W3,
    const float* __restrict__ b3, float* __restrict__ out, int M) {
  const int lane = threadIdx.x & 63;
  const int w = threadIdx.x >> 6;
  const int row = blockIdx.x * 4 + w;
  if (row >= M) return;
  const f16* hr = H + (size_t)row * DFC;
  float s = 0.f;
#pragma unroll
  for (int k = 0; k < 2; ++k) {
    int j = (lane + k * 64) * 8;
    f16x8 hv = *(const f16x8*)&hr[j];
    float4 w0 = *(const float4*)&W3[j];
    float4 w1 = *(const float4*)&W3[j + 4];
    s += (float)hv[0] * w0.x + (float)hv[1] * w0.y +
         (float)hv[2] * w0.z + (float)hv[3] * w0.w +
         (float)hv[4] * w1.x + (float)hv[5] * w1.y +
         (float)hv[6] * w1.z + (float)hv[7] * w1.w;
  }
  for (int off = 32; off; off >>= 1) s += __shfl_xor(s, off);
  if (lane == 0) out[row] = s + b3[0];
}

extern "C" void kernel_launch(void* const* d_in, const int* in_sizes, int n_in,
                              void* d_out, int out_size, void* d_ws, size_t ws_size,
                              hipStream_t stream) {
  const float* feature = (const float*)d_in[0];
  const float* p       = (const float*)d_in[1];
  const float* feat    = (const float*)d_in[2];
  const float* W_fc1   = (const float*)d_in[3];
  const float* b_fc1   = (const float*)d_in[4];
  const float* W1      = (const float*)d_in[5];
  const float* b1      = (const float*)d_in[6];
  const float* W2      = (const float*)d_in[7];
  const float* b2      = (const float*)d_in[8];
  const float* W3      = (const float*)d_in[9];
  const float* b3      = (const float*)d_in[10];
  float* out = (float*)d_out;

  char* ws = (char*)d_ws;
  f16* x   = (f16*)(ws + 0);                    //  33,554,432 B
  f16* z   = (f16*)(ws + 33554432ULL);          //  87,040,000 B (40000x1088)
  f16* h1  = (f16*)(ws + 120594432ULL);         //  81,920,000 B (40000x1024)
  f16* W1t = (f16*)(ws + 202514432ULL);         //   2,228,224 B (1024x1088)
  f16* W2t = (f16*)(ws + 204742656ULL);         //   2,097,152 B (1024x1024)
  f16* h2  = z;  // z dead after gemm1

  hipLaunchKernelGGL(wtrans_kernel, dim3(32, 34), dim3(256), 0, stream,
                     W1, W1t, 1032, KP1);
  hipLaunchKernelGGL(wtrans_kernel, dim3(32, 32), dim3(256), 0, stream,
                     W2, W2t, 1024, 1024);
  hipLaunchKernelGGL(conv1x1_kernel, dim3(64, 8), dim3(256), 0, stream,
                     feature, W_fc1, b_fc1, x);
  hipLaunchKernelGGL(sample_kernel, dim3(5000), dim3(256), 0, stream,
                     x, p, feat, z);
  hipLaunchKernelGGL(gemm_f16, dim3(2504), dim3(256), 0, stream,
                     z, W1t, b1, h1, LROWS, KP1 / 64, KP1);
  hipLaunchKernelGGL(gemm_f16, dim3(2504), dim3(256), 0, stream,
                     h1, W2t, b2, h2, LROWS, DFC / 64, DFC);
  hipLaunchKernelGGL(fc3_kernel, dim3(10000), dim3(256), 0, stream,
                     h2, W3, b3, out, LROWS);
}

// Round 3
// 511.588 us; speedup vs baseline: 6.0190x; 1.4479x over previous
//
#include <hip/hip_runtime.h>

typedef _Float16 f16;
typedef f16 f16x8 __attribute__((ext_vector_type(8)));
typedef float f32x4 __attribute__((ext_vector_type(4)));

#define HW    128
#define NPIX  16384      // 128*128
#define CDIM  256
#define DLOI  128
#define LROWS 40000      // B*L
#define DFC   1024
#define KP1   1088       // fc1 K (1032) padded to 17*64

// ---------------- conv1x1: x[b][pix][d] (fp16) = sum_c feature[b][c][pix] * W[d][c] + bias
__global__ __launch_bounds__(256) void conv1x1_kernel(
    const float* __restrict__ feature, const float* __restrict__ Wfc,
    const float* __restrict__ bfc, f16* __restrict__ x) {
  __shared__ float Wl[64][128];
  const int tid = threadIdx.x;
  const int b = blockIdx.y;
  const int pixbase = blockIdx.x * 256;
  const int dh = tid & 3;
  const int pp = tid >> 2;
  const float* fb = feature + (size_t)b * CDIM * NPIX + pixbase;

  float acc[4][32];
#pragma unroll
  for (int j = 0; j < 4; ++j)
#pragma unroll
    for (int dd = 0; dd < 32; ++dd) acc[j][dd] = 0.f;

  for (int cc = 0; cc < CDIM; cc += 64) {
    __syncthreads();
    for (int e = tid; e < 64 * 128; e += 256) {
      int c = e >> 7, d = e & 127;
      Wl[c][d] = Wfc[d * CDIM + cc + c];
    }
    __syncthreads();
    for (int c = 0; c < 64; ++c) {
      float f0 = fb[(size_t)(cc + c) * NPIX + pp];
      float f1 = fb[(size_t)(cc + c) * NPIX + pp + 64];
      float f2 = fb[(size_t)(cc + c) * NPIX + pp + 128];
      float f3 = fb[(size_t)(cc + c) * NPIX + pp + 192];
      const float* wrow = &Wl[c][dh * 32];
#pragma unroll
      for (int dd = 0; dd < 32; ++dd) {
        float w = wrow[dd];
        acc[0][dd] += f0 * w; acc[1][dd] += f1 * w;
        acc[2][dd] += f2 * w; acc[3][dd] += f3 * w;
      }
    }
  }
  float bv[32];
#pragma unroll
  for (int dd = 0; dd < 32; ++dd) bv[dd] = bfc[dh * 32 + dd];
#pragma unroll
  for (int j = 0; j < 4; ++j) {
    size_t pix = (size_t)pixbase + pp + j * 64;
    f16* xo = x + ((size_t)b * NPIX + pix) * DLOI + dh * 32;
#pragma unroll
    for (int dd = 0; dd < 32; ++dd)
      xo[dd] = (f16)(acc[j][dd] + bv[dd]);
  }
}

// ---------------- sampling + bilinear + maxpool(4) + concat -> z[40000][1088] fp16
// z K-layout: k' = q*128 + c  (pool-group major); W1t is built with the inverse perm.
// Wave = 1 line; 4 sub-groups of 16 lanes; sub-group = 1 pool group, lane = 8 channels.
// Corner reads are 16x16B contiguous per sub-group; pooled store is 16B/lane contiguous.
__global__ __launch_bounds__(256) void sample_kernel(
    const f16* __restrict__ x, const float* __restrict__ p,
    const float* __restrict__ feat, f16* __restrict__ z) {
  const int tid = threadIdx.x;
  const int wv = tid >> 6;
  const int lane = tid & 63;
  const int sub = lane >> 4;           // pool group within half
  const int cl = lane & 15;            // channel block (8 ch)
  const int bid = blockIdx.x;          // 0..9999
  const int b = bid & 7;               // batch -> XCD pin
  const int row = b * 5000 + (bid >> 3) * 4 + wv;

  const float4 pe = *(const float4*)&p[(size_t)row * 4]; // p0x p0y p1x p1y
  const size_t bb = (size_t)b * NPIX;
  f16* zr = z + (size_t)row * KP1;

#pragma unroll
  for (int gh = 0; gh < 2; ++gh) {
    const int g = gh * 4 + sub;        // pool group 0..7
    float acc[8];
#pragma unroll
    for (int ci = 0; ci < 8; ++ci) acc[ci] = -1e30f;
#pragma unroll
    for (int pt = 0; pt < 4; ++pt) {
      const int t = g * 4 + pt;
      const float lam = (float)t * (1.0f / 31.0f);
      const float px = pe.x * lam + pe.z * (1.f - lam) - 0.5f;
      const float py = pe.y * lam + pe.w * (1.f - lam) - 0.5f;
      const float px0 = fminf(fmaxf(floorf(px), 0.f), 127.f);
      const float py0 = fminf(fmaxf(floorf(py), 0.f), 127.f);
      const float px1 = fminf(px0 + 1.f, 127.f);
      const float py1 = fminf(py0 + 1.f, 127.f);
      const int ix0 = (int)px0, iy0 = (int)py0, ix1 = (int)px1, iy1 = (int)py1;
      const float w00 = (px1 - px) * (py1 - py);
      const float w10 = (px - px0) * (py1 - py);
      const float w01 = (px1 - px) * (py - py0);
      const float w11 = (px - px0) * (py - py0);

      const f16* r00 = x + (bb + ix0 * HW + iy0) * DLOI + cl * 8;
      const f16* r10 = x + (bb + ix1 * HW + iy0) * DLOI + cl * 8;
      const f16* r01 = x + (bb + ix0 * HW + iy1) * DLOI + cl * 8;
      const f16* r11 = x + (bb + ix1 * HW + iy1) * DLOI + cl * 8;
      f16x8 a  = *(const f16x8*)r00;
      f16x8 bq = *(const f16x8*)r10;
      f16x8 cq = *(const f16x8*)r01;
      f16x8 dq = *(const f16x8*)r11;
#pragma unroll
      for (int ci = 0; ci < 8; ++ci) {
        float m = w00 * (float)a[ci] + w10 * (float)bq[ci] +
                  w01 * (float)cq[ci] + w11 * (float)dq[ci];
        acc[ci] = fmaxf(acc[ci], m);
      }
    }
    f16x8 o;
#pragma unroll
    for (int ci = 0; ci < 8; ++ci) o[ci] = (f16)acc[ci];
    *(f16x8*)(zr + g * 128 + cl * 8) = o;
  }
  if (lane < 8) zr[1024 + lane] = (f16)feat[(size_t)row * 8 + lane];
  else if (lane < 36) *(unsigned int*)((char*)zr + 2064 + (lane - 8) * 4) = 0u;
}

// ---------------- weight transpose + fp16 + K-pad (+ optional k-permute for z layout)
// Wt[n][k'] = (f16) W[src(k')][n];  src(k') = (k'&127)*8 + (k'>>7) if permute && k'<1024
__global__ __launch_bounds__(256) void wtrans_kernel(
    const float* __restrict__ W, f16* __restrict__ Wt, int K, int ldt, int permute) {
  __shared__ float t[32][33];
  const int tx = threadIdx.x & 31, ty = threadIdx.x >> 5;
#pragma unroll
  for (int i = 0; i < 4; ++i) {
    int kd = blockIdx.y * 32 + ty + i * 8;
    int ks = (permute && kd < 1024) ? ((kd & 127) * 8 + (kd >> 7)) : kd;
    int n = blockIdx.x * 32 + tx;
    t[ty + i * 8][tx] = (ks < K) ? W[(size_t)ks * DFC + n] : 0.f;
  }
  __syncthreads();
#pragma unroll
  for (int i = 0; i < 4; ++i) {
    int n = blockIdx.x * 32 + ty + i * 8;
    int k = blockIdx.y * 32 + tx;
    Wt[(size_t)n * ldt + k] = (f16)t[tx][ty + i * 8];
  }
}

// ---------------- fp16 MFMA GEMM: C[M][1024] = relu_f16(A[M][lda] @ Bt[1024][lda]^T + bias)
// 128x128 tile, BK=64, global_load_lds + XOR-swizzled LDS (slot ^ (row&7))
__global__ __launch_bounds__(256) void gemm_f16(
    const f16* __restrict__ A, const f16* __restrict__ Bt,
    const float* __restrict__ bias, f16* __restrict__ C,
    int M, int ksteps, int lda) {
  __shared__ f16 As[128 * 64];
  __shared__ f16 Bs[128 * 64];
  const int tid = threadIdx.x;
  const int l = tid & 63;
  const int w = tid >> 6;

  const int nwg = gridDim.x;            // 2504 (313 m-tiles x 8 n-tiles)
  const int s = (blockIdx.x & 7) * (nwg >> 3) + (blockIdx.x >> 3);
  const int m0 = (s >> 3) * 128;
  const int n0 = (s & 7) * 128;

  const int wr = (w >> 1) * 64, wc = (w & 1) * 64;
  const int srow = w * 8 + (l >> 3);
  const int slot = l & 7;

  f32x4 acc[4][4] = {};

  for (int kt = 0; kt < ksteps; ++kt) {
    const int kb = kt * 64;
    __syncthreads();
#pragma unroll
    for (int c = 0; c < 4; ++c) {
      int row = c * 32 + srow;
      int arow = m0 + row; if (arow >= M) arow = M - 1;
      const f16* g = A + (size_t)arow * lda + kb + ((slot ^ (row & 7)) * 8);
      __builtin_amdgcn_global_load_lds(
          (const __attribute__((address_space(1))) void*)g,
          (__attribute__((address_space(3))) void*)(As + row * 64 + slot * 8),
          16, 0, 0);
    }
#pragma unroll
    for (int c = 0; c < 4; ++c) {
      int row = c * 32 + srow;
      const f16* g = Bt + (size_t)(n0 + row) * lda + kb + ((slot ^ (row & 7)) * 8);
      __builtin_amdgcn_global_load_lds(
          (const __attribute__((address_space(1))) void*)g,
          (__attribute__((address_space(3))) void*)(Bs + row * 64 + slot * 8),
          16, 0, 0);
    }
    __syncthreads();

    const int lrow = l & 15;
    const int g4 = l >> 4;
#pragma unroll
    for (int kh = 0; kh < 2; ++kh) {
      f16x8 af[4], bf[4];
#pragma unroll
      for (int m = 0; m < 4; ++m) {
        int row = wr + m * 16 + lrow;
        int sl = (g4 + 4 * kh) ^ (row & 7);
        af[m] = *(const f16x8*)(As + row * 64 + sl * 8);
      }
#pragma unroll
      for (int n = 0; n < 4; ++n) {
        int row = wc + n * 16 + lrow;
        int sl = (g4 + 4 * kh) ^ (row & 7);
        bf[n] = *(const f16x8*)(Bs + row * 64 + sl * 8);
      }
#pragma unroll
      for (int m = 0; m < 4; ++m)
#pragma unroll
        for (int n = 0; n < 4; ++n)
          acc[m][n] = __builtin_amdgcn_mfma_f32_16x16x32_f16(af[m], bf[n], acc[m][n], 0, 0, 0);
    }
  }

  const int ocol0 = n0 + wc + (l & 15);
  const int orow0 = m0 + wr + (l >> 4) * 4;
#pragma unroll
  for (int m = 0; m < 4; ++m) {
#pragma unroll
    for (int r = 0; r < 4; ++r) {
      int orow = orow0 + m * 16 + r;
      if (orow >= M) continue;
      f16* crow = C + (size_t)orow * DFC;
#pragma unroll
      for (int n = 0; n < 4; ++n) {
        int col = ocol0 + n * 16;
        float v = acc[m][n][r] + bias[col];
        crow[col] = (f16)fmaxf(v, 0.f);
      }
    }
  }
}

// ---------------- fc3: out[m] = h2[m] . W3 + b3   (h2 fp16, W3 fp32)
__global__ __launch_bounds__(256) void fc3_kernel(
    const f16* __restrict__ H, const float* __restrict__ W3,
    const float* __restrict__ b3, float* __restrict__ out, int M) {
  const int lane = threadIdx.x & 63;
  const int w = threadIdx.x >> 6;
  const int row = blockIdx.x * 4 + w;
  if (row >= M) return;
  const f16* hr = H + (size_t)row * DFC;
  float s = 0.f;
#pragma unroll
  for (int k = 0; k < 2; ++k) {
    int j = (lane + k * 64) * 8;
    f16x8 hv = *(const f16x8*)&hr[j];
    float4 w0 = *(const float4*)&W3[j];
    float4 w1 = *(const float4*)&W3[j + 4];
    s += (float)hv[0] * w0.x + (float)hv[1] * w0.y +
         (float)hv[2] * w0.z + (float)hv[3] * w0.w +
         (float)hv[4] * w1.x + (float)hv[5] * w1.y +
         (float)hv[6] * w1.z + (float)hv[7] * w1.w;
  }
  for (int off = 32; off; off >>= 1) s += __shfl_xor(s, off);
  if (lane == 0) out[row] = s + b3[0];
}

extern "C" void kernel_launch(void* const* d_in, const int* in_sizes, int n_in,
                              void* d_out, int out_size, void* d_ws, size_t ws_size,
                              hipStream_t stream) {
  const float* feature = (const float*)d_in[0];
  const float* p       = (const float*)d_in[1];
  const float* feat    = (const float*)d_in[2];
  const float* W_fc1   = (const float*)d_in[3];
  const float* b_fc1   = (const float*)d_in[4];
  const float* W1      = (const float*)d_in[5];
  const float* b1      = (const float*)d_in[6];
  const float* W2      = (const float*)d_in[7];
  const float* b2      = (const float*)d_in[8];
  const float* W3      = (const float*)d_in[9];
  const float* b3      = (const float*)d_in[10];
  float* out = (float*)d_out;

  char* ws = (char*)d_ws;
  f16* x   = (f16*)(ws + 0);                    //  33,554,432 B
  f16* z   = (f16*)(ws + 33554432ULL);          //  87,040,000 B (40000x1088)
  f16* h1  = (f16*)(ws + 120594432ULL);         //  81,920,000 B (40000x1024)
  f16* W1t = (f16*)(ws + 202514432ULL);         //   2,228,224 B (1024x1088)
  f16* W2t = (f16*)(ws + 204742656ULL);         //   2,097,152 B (1024x1024)
  f16* h2  = z;  // z dead after gemm1

  hipLaunchKernelGGL(wtrans_kernel, dim3(32, 34), dim3(256), 0, stream,
                     W1, W1t, 1032, KP1, 1);
  hipLaunchKernelGGL(wtrans_kernel, dim3(32, 32), dim3(256), 0, stream,
                     W2, W2t, 1024, 1024, 0);
  hipLaunchKernelGGL(conv1x1_kernel, dim3(64, 8), dim3(256), 0, stream,
                     feature, W_fc1, b_fc1, x);
  hipLaunchKernelGGL(sample_kernel, dim3(10000), dim3(256), 0, stream,
                     x, p, feat, z);
  hipLaunchKernelGGL(gemm_f16, dim3(2504), dim3(256), 0, stream,
                     z, W1t, b1, h1, LROWS, KP1 / 64, KP1);
  hipLaunchKernelGGL(gemm_f16, dim3(2504), dim3(256), 0, stream,
                     h1, W2t, b2, h2, LROWS, DFC / 64, DFC);
  hipLaunchKernelGGL(fc3_kernel, dim3(10000), dim3(256), 0, stream,
                     h2, W3, b3, out, LROWS);
}

// Round 5
// 436.586 us; speedup vs baseline: 7.0529x; 1.1718x over previous
//
#include <hip/hip_runtime.h>

typedef _Float16 f16;
typedef __fp16 h16x2 __attribute__((ext_vector_type(2)));
typedef f16 f16x8 __attribute__((ext_vector_type(8)));
typedef float f32x4 __attribute__((ext_vector_type(4)));

#define HW    128
#define NPIX  16384      // 128*128
#define CDIM  256
#define DLOI  128
#define LROWS 40000      // B*L
#define DFC   1024
#define KP1   1088       // fc1 K (1032) padded to 17*64

// ---------------- conv1x1 via v_dot2_f32_f16: x[b][pix][d] (f16)
// wave = d-quarter (dh uniform -> all W reads broadcast, zero bank conflicts)
// lane = pix; 128-pix tile/block -> 1024 blocks (4/CU)
__global__ __launch_bounds__(256, 4) void conv1x1_kernel(
    const float* __restrict__ feature, const float* __restrict__ Wfc,
    const float* __restrict__ bfc, f16* __restrict__ x) {
  __shared__ h16x2 Wl2[32][132];       // [c-pair][d], padded row
  const int tid = threadIdx.x;
  const int lane = tid & 63;
  const int dh = tid >> 6;             // wave id: d-quarter, wave-uniform
  const int b = blockIdx.y;
  const int p0 = blockIdx.x * 128 + lane;     // and p0+64
  const float* fb = feature + (size_t)b * CDIM * NPIX;

  float acc0[32], acc1[32];
#pragma unroll
  for (int dd = 0; dd < 32; ++dd) { acc0[dd] = 0.f; acc1[dd] = 0.f; }

  for (int cc = 0; cc < CDIM; cc += 64) {
    __syncthreads();
    {  // stage W c-pairs: lanes along c (coalesced 256B rows of W)
      const int cq = tid & 15;         // c-quad within chunk
      const int dbase = tid >> 4;      // 0..15
#pragma unroll
      for (int pass = 0; pass < 8; ++pass) {
        int d = pass * 16 + dbase;
        float4 wv = *(const float4*)&Wfc[(size_t)d * CDIM + cc + cq * 4];
        Wl2[cq * 2 + 0][d] = __builtin_amdgcn_cvt_pkrtz(wv.x, wv.y);
        Wl2[cq * 2 + 1][d] = __builtin_amdgcn_cvt_pkrtz(wv.z, wv.w);
      }
    }
    __syncthreads();
    const float* f0 = fb + (size_t)cc * NPIX + p0;
#pragma unroll 2
    for (int cp = 0; cp < 32; ++cp) {
      float va0 = f0[0],    va1 = f0[64];
      float vb0 = f0[NPIX], vb1 = f0[NPIX + 64];
      h16x2 pa0 = __builtin_amdgcn_cvt_pkrtz(va0, vb0);
      h16x2 pa1 = __builtin_amdgcn_cvt_pkrtz(va1, vb1);
      const h16x2* wrow = &Wl2[cp][dh * 32];
#pragma unroll
      for (int dd = 0; dd < 32; ++dd) {
        h16x2 w2 = wrow[dd];
        acc0[dd] = __builtin_amdgcn_fdot2(pa0, w2, acc0[dd], false);
        acc1[dd] = __builtin_amdgcn_fdot2(pa1, w2, acc1[dd], false);
      }
      f0 += 2 * NPIX;
    }
  }
  f16* xo0 = x + ((size_t)b * NPIX + p0) * DLOI + dh * 32;
  f16* xo1 = xo0 + 64 * DLOI;
  const float* bp = bfc + dh * 32;
#pragma unroll
  for (int dd = 0; dd < 32; ++dd) {
    xo0[dd] = (f16)(acc0[dd] + bp[dd]);
    xo1[dd] = (f16)(acc1[dd] + bp[dd]);
  }
}

// ---------------- sampling + bilinear + maxpool(4) + concat -> z[40000][1088] fp16
// z K-layout: k' = q*128 + c  (pool-group major); W1t is built with the inverse perm.
__global__ __launch_bounds__(256) void sample_kernel(
    const f16* __restrict__ x, const float* __restrict__ p,
    const float* __restrict__ feat, f16* __restrict__ z) {
  const int tid = threadIdx.x;
  const int wv = tid >> 6;
  const int lane = tid & 63;
  const int sub = lane >> 4;           // pool group within half
  const int cl = lane & 15;            // channel block (8 ch)
  const int bid = blockIdx.x;          // 0..9999
  const int b = bid & 7;               // batch -> XCD pin
  const int row = b * 5000 + (bid >> 3) * 4 + wv;

  const float4 pe = *(const float4*)&p[(size_t)row * 4]; // p0x p0y p1x p1y
  const size_t bb = (size_t)b * NPIX;
  f16* zr = z + (size_t)row * KP1;

#pragma unroll
  for (int gh = 0; gh < 2; ++gh) {
    const int g = gh * 4 + sub;        // pool group 0..7
    float acc[8];
#pragma unroll
    for (int ci = 0; ci < 8; ++ci) acc[ci] = -1e30f;
#pragma unroll
    for (int pt = 0; pt < 4; ++pt) {
      const int t = g * 4 + pt;
      const float lam = (float)t * (1.0f / 31.0f);
      const float px = pe.x * lam + pe.z * (1.f - lam) - 0.5f;
      const float py = pe.y * lam + pe.w * (1.f - lam) - 0.5f;
      const float px0 = fminf(fmaxf(floorf(px), 0.f), 127.f);
      const float py0 = fminf(fmaxf(floorf(py), 0.f), 127.f);
      const float px1 = fminf(px0 + 1.f, 127.f);
      const float py1 = fminf(py0 + 1.f, 127.f);
      const int ix0 = (int)px0, iy0 = (int)py0, ix1 = (int)px1, iy1 = (int)py1;
      const float w00 = (px1 - px) * (py1 - py);
      const float w10 = (px - px0) * (py1 - py);
      const float w01 = (px1 - px) * (py - py0);
      const float w11 = (px - px0) * (py - py0);

      const f16* r00 = x + (bb + ix0 * HW + iy0) * DLOI + cl * 8;
      const f16* r10 = x + (bb + ix1 * HW + iy0) * DLOI + cl * 8;
      const f16* r01 = x + (bb + ix0 * HW + iy1) * DLOI + cl * 8;
      const f16* r11 = x + (bb + ix1 * HW + iy1) * DLOI + cl * 8;
      f16x8 a  = *(const f16x8*)r00;
      f16x8 bq = *(const f16x8*)r10;
      f16x8 cq = *(const f16x8*)r01;
      f16x8 dq = *(const f16x8*)r11;
#pragma unroll
      for (int ci = 0; ci < 8; ++ci) {
        float m = w00 * (float)a[ci] + w10 * (float)bq[ci] +
                  w01 * (float)cq[ci] + w11 * (float)dq[ci];
        acc[ci] = fmaxf(acc[ci], m);
      }
    }
    f16x8 o;
#pragma unroll
    for (int ci = 0; ci < 8; ++ci) o[ci] = (f16)acc[ci];
    *(f16x8*)(zr + g * 128 + cl * 8) = o;
  }
  if (lane < 8) zr[1024 + lane] = (f16)feat[(size_t)row * 8 + lane];
  else if (lane < 36) *(unsigned int*)((char*)zr + 2064 + (lane - 8) * 4) = 0u;
}

// ---------------- weight transpose + fp16 + K-pad (+ optional k-permute for z layout)
__global__ __launch_bounds__(256) void wtrans_kernel(
    const float* __restrict__ W, f16* __restrict__ Wt, int K, int ldt, int permute) {
  __shared__ float t[32][33];
  const int tx = threadIdx.x & 31, ty = threadIdx.x >> 5;
#pragma unroll
  for (int i = 0; i < 4; ++i) {
    int kd = blockIdx.y * 32 + ty + i * 8;
    int ks = (permute && kd < 1024) ? ((kd & 127) * 8 + (kd >> 7)) : kd;
    int n = blockIdx.x * 32 + tx;
    t[ty + i * 8][tx] = (ks < K) ? W[(size_t)ks * DFC + n] : 0.f;
  }
  __syncthreads();
#pragma unroll
  for (int i = 0; i < 4; ++i) {
    int n = blockIdx.x * 32 + ty + i * 8;
    int k = blockIdx.y * 32 + tx;
    Wt[(size_t)n * ldt + k] = (f16)t[tx][ty + i * 8];
  }
}

// ---------------- fp16 MFMA GEMM: C[M][1024] = relu_f16(A[M][lda] @ Bt[1024][lda]^T + bias)
__global__ __launch_bounds__(256) void gemm_f16(
    const f16* __restrict__ A, const f16* __restrict__ Bt,
    const float* __restrict__ bias, f16* __restrict__ C,
    int M, int ksteps, int lda) {
  __shared__ f16 As[128 * 64];
  __shared__ f16 Bs[128 * 64];
  const int tid = threadIdx.x;
  const int l = tid & 63;
  const int w = tid >> 6;

  const int nwg = gridDim.x;            // 2504 (313 m-tiles x 8 n-tiles)
  const int s = (blockIdx.x & 7) * (nwg >> 3) + (blockIdx.x >> 3);
  const int m0 = (s >> 3) * 128;
  const int n0 = (s & 7) * 128;

  const int wr = (w >> 1) * 64, wc = (w & 1) * 64;
  const int srow = w * 8 + (l >> 3);
  const int slot = l & 7;

  f32x4 acc[4][4] = {};

  for (int kt = 0; kt < ksteps; ++kt) {
    const int kb = kt * 64;
    __syncthreads();
#pragma unroll
    for (int c = 0; c < 4; ++c) {
      int row = c * 32 + srow;
      int arow = m0 + row; if (arow >= M) arow = M - 1;
      const f16* g = A + (size_t)arow * lda + kb + ((slot ^ (row & 7)) * 8);
      __builtin_amdgcn_global_load_lds(
          (const __attribute__((address_space(1))) void*)g,
          (__attribute__((address_space(3))) void*)(As + row * 64 + slot * 8),
          16, 0, 0);
    }
#pragma unroll
    for (int c = 0; c < 4; ++c) {
      int row = c * 32 + srow;
      const f16* g = Bt + (size_t)(n0 + row) * lda + kb + ((slot ^ (row & 7)) * 8);
      __builtin_amdgcn_global_load_lds(
          (const __attribute__((address_space(1))) void*)g,
          (__attribute__((address_space(3))) void*)(Bs + row * 64 + slot * 8),
          16, 0, 0);
    }
    __syncthreads();

    const int lrow = l & 15;
    const int g4 = l >> 4;
#pragma unroll
    for (int kh = 0; kh < 2; ++kh) {
      f16x8 af[4], bf[4];
#pragma unroll
      for (int m = 0; m < 4; ++m) {
        int row = wr + m * 16 + lrow;
        int sl = (g4 + 4 * kh) ^ (row & 7);
        af[m] = *(const f16x8*)(As + row * 64 + sl * 8);
      }
#pragma unroll
      for (int n = 0; n < 4; ++n) {
        int row = wc + n * 16 + lrow;
        int sl = (g4 + 4 * kh) ^ (row & 7);
        bf[n] = *(const f16x8*)(Bs + row * 64 + sl * 8);
      }
#pragma unroll
      for (int m = 0; m < 4; ++m)
#pragma unroll
        for (int n = 0; n < 4; ++n)
          acc[m][n] = __builtin_amdgcn_mfma_f32_16x16x32_f16(af[m], bf[n], acc[m][n], 0, 0, 0);
    }
  }

  const int ocol0 = n0 + wc + (l & 15);
  const int orow0 = m0 + wr + (l >> 4) * 4;
#pragma unroll
  for (int m = 0; m < 4; ++m) {
#pragma unroll
    for (int r = 0; r < 4; ++r) {
      int orow = orow0 + m * 16 + r;
      if (orow >= M) continue;
      f16* crow = C + (size_t)orow * DFC;
#pragma unroll
      for (int n = 0; n < 4; ++n) {
        int col = ocol0 + n * 16;
        float v = acc[m][n][r] + bias[col];
        crow[col] = (f16)fmaxf(v, 0.f);
      }
    }
  }
}

// ---------------- fc3: out[m] = h2[m] . W3 + b3   (h2 fp16, W3 fp32)
__global__ __launch_bounds__(256) void fc3_kernel(
    const f16* __restrict__ H, const float* __restrict__ W3,
    const float* __restrict__ b3, float* __restrict__ out, int M) {
  const int lane = threadIdx.x & 63;
  const int w = threadIdx.x >> 6;
  const int row = blockIdx.x * 4 + w;
  if (row >= M) return;
  const f16* hr = H + (size_t)row * DFC;
  float s = 0.f;
#pragma unroll
  for (int k = 0; k < 2; ++k) {
    int j = (lane + k * 64) * 8;
    f16x8 hv = *(const f16x8*)&hr[j];
    float4 w0 = *(const float4*)&W3[j];
    float4 w1 = *(const float4*)&W3[j + 4];
    s += (float)hv[0] * w0.x + (float)hv[1] * w0.y +
         (float)hv[2] * w0.z + (float)hv[3] * w0.w +
         (float)hv[4] * w1.x + (float)hv[5] * w1.y +
         (float)hv[6] * w1.z + (float)hv[7] * w1.w;
  }
  for (int off = 32; off; off >>= 1) s += __shfl_xor(s, off);
  if (lane == 0) out[row] = s + b3[0];
}

extern "C" void kernel_launch(void* const* d_in, const int* in_sizes, int n_in,
                              void* d_out, int out_size, void* d_ws, size_t ws_size,
                              hipStream_t stream) {
  const float* feature = (const float*)d_in[0];
  const float* p       = (const float*)d_in[1];
  const float* feat    = (const float*)d_in[2];
  const float* W_fc1   = (const float*)d_in[3];
  const float* b_fc1   = (const float*)d_in[4];
  const float* W1      = (const float*)d_in[5];
  const float* b1      = (const float*)d_in[6];
  const float* W2      = (const float*)d_in[7];
  const float* b2      = (const float*)d_in[8];
  const float* W3      = (const float*)d_in[9];
  const float* b3      = (const float*)d_in[10];
  float* out = (float*)d_out;

  char* ws = (char*)d_ws;
  f16* x   = (f16*)(ws + 0);                    //  33,554,432 B
  f16* z   = (f16*)(ws + 33554432ULL);          //  87,040,000 B (40000x1088)
  f16* h1  = (f16*)(ws + 120594432ULL);         //  81,920,000 B (40000x1024)
  f16* W1t = (f16*)(ws + 202514432ULL);         //   2,228,224 B (1024x1088)
  f16* W2t = (f16*)(ws + 204742656ULL);         //   2,097,152 B (1024x1024)
  f16* h2  = z;  // z dead after gemm1

  hipLaunchKernelGGL(wtrans_kernel, dim3(32, 34), dim3(256), 0, stream,
                     W1, W1t, 1032, KP1, 1);
  hipLaunchKernelGGL(wtrans_kernel, dim3(32, 32), dim3(256), 0, stream,
                     W2, W2t, 1024, 1024, 0);
  hipLaunchKernelGGL(conv1x1_kernel, dim3(128, 8), dim3(256), 0, stream,
                     feature, W_fc1, b_fc1, x);
  hipLaunchKernelGGL(sample_kernel, dim3(10000), dim3(256), 0, stream,
                     x, p, feat, z);
  hipLaunchKernelGGL(gemm_f16, dim3(2504), dim3(256), 0, stream,
                     z, W1t, b1, h1, LROWS, KP1 / 64, KP1);
  hipLaunchKernelGGL(gemm_f16, dim3(2504), dim3(256), 0, stream,
                     h1, W2t, b2, h2, LROWS, DFC / 64, DFC);
  hipLaunchKernelGGL(fc3_kernel, dim3(10000), dim3(256), 0, stream,
                     h2, W3, b3, out, LROWS);
}

// Round 6
// 380.346 us; speedup vs baseline: 8.0958x; 1.1479x over previous
//
#include <hip/hip_runtime.h>

typedef _Float16 f16;
typedef __fp16 h16x2 __attribute__((ext_vector_type(2)));
typedef f16 f16x8 __attribute__((ext_vector_type(8)));
typedef float f32x4 __attribute__((ext_vector_type(4)));

#define HW    128
#define NPIX  16384      // 128*128
#define CDIM  256
#define DLOI  128
#define LROWS 40000      // B*L
#define DFC   1024
#define KP1   1088       // fc1 K (1032) padded to 17*64

// ---------------- conv1x1 as register-only MFMA GEMM: x[b][pix][d] (f16)
// C[M=16384 pix][N=128 d] = feature^T[pix][c] @ W^T[c][d], K=256, per batch.
// A-frag: lane reads feature[c..][pix] -> 4 c-rows x 16 consecutive pix per
// instr (coalesced 64B segments). B-frag: W[d][c] 32B contiguous, L2-resident.
// fp32->f16 via cvt_pkrtz in-register. No LDS, no barriers.
__global__ __launch_bounds__(256, 4) void conv1x1_kernel(
    const float* __restrict__ feature, const float* __restrict__ Wfc,
    const float* __restrict__ bfc, f16* __restrict__ x) {
  const int tid = threadIdx.x;
  const int l = tid & 63;
  const int w = tid >> 6;
  const int b = blockIdx.y;
  const int pix0 = blockIdx.x * 128;
  const int wr = (w >> 1) * 64;        // wave pix offset
  const int wc = (w & 1) * 64;         // wave d offset
  const int lrow = l & 15;
  const int g4 = l >> 4;

  const float* fb = feature + (size_t)b * CDIM * NPIX;
  f32x4 acc[4][4] = {};

  for (int kf = 0; kf < 8; ++kf) {     // 32 c per k-frag
    const int kb = kf * 32 + g4 * 8;   // this lane's 8 consecutive c
    f16x8 bf[4];
#pragma unroll
    for (int n = 0; n < 4; ++n) {
      const float* wp = &Wfc[(size_t)(wc + n * 16 + lrow) * CDIM + kb];
      float4 w0 = *(const float4*)wp;
      float4 w1 = *(const float4*)(wp + 4);
      union { f16x8 v; h16x2 h[4]; } u;
      u.h[0] = __builtin_amdgcn_cvt_pkrtz(w0.x, w0.y);
      u.h[1] = __builtin_amdgcn_cvt_pkrtz(w0.z, w0.w);
      u.h[2] = __builtin_amdgcn_cvt_pkrtz(w1.x, w1.y);
      u.h[3] = __builtin_amdgcn_cvt_pkrtz(w1.z, w1.w);
      bf[n] = u.v;
    }
#pragma unroll
    for (int m = 0; m < 4; ++m) {
      const int pix = pix0 + wr + m * 16 + lrow;
      const float* ap = fb + (size_t)kb * NPIX + pix;
      float av[8];
#pragma unroll
      for (int j = 0; j < 8; ++j) av[j] = ap[(size_t)j * NPIX];
      union { f16x8 v; h16x2 h[4]; } u;
      u.h[0] = __builtin_amdgcn_cvt_pkrtz(av[0], av[1]);
      u.h[1] = __builtin_amdgcn_cvt_pkrtz(av[2], av[3]);
      u.h[2] = __builtin_amdgcn_cvt_pkrtz(av[4], av[5]);
      u.h[3] = __builtin_amdgcn_cvt_pkrtz(av[6], av[7]);
#pragma unroll
      for (int n = 0; n < 4; ++n)
        acc[m][n] = __builtin_amdgcn_mfma_f32_16x16x32_f16(u.v, bf[n], acc[m][n], 0, 0, 0);
    }
  }

  // C/D layout: col = l&15, row = (l>>4)*4 + r
#pragma unroll
  for (int m = 0; m < 4; ++m) {
#pragma unroll
    for (int r = 0; r < 4; ++r) {
      const int pix = pix0 + wr + m * 16 + g4 * 4 + r;
      f16* xr = x + ((size_t)b * NPIX + pix) * DLOI;
#pragma unroll
      for (int n = 0; n < 4; ++n) {
        const int d = wc + n * 16 + lrow;
        xr[d] = (f16)(acc[m][n][r] + bfc[d]);
      }
    }
  }
}

// ---------------- sampling + bilinear + maxpool(4) + concat -> z[40000][1088] fp16
// z K-layout: k' = q*128 + c  (pool-group major); W1t is built with the inverse perm.
__global__ __launch_bounds__(256) void sample_kernel(
    const f16* __restrict__ x, const float* __restrict__ p,
    const float* __restrict__ feat, f16* __restrict__ z) {
  const int tid = threadIdx.x;
  const int wv = tid >> 6;
  const int lane = tid & 63;
  const int sub = lane >> 4;           // pool group within half
  const int cl = lane & 15;            // channel block (8 ch)
  const int bid = blockIdx.x;          // 0..9999
  const int b = bid & 7;               // batch -> XCD pin
  const int row = b * 5000 + (bid >> 3) * 4 + wv;

  const float4 pe = *(const float4*)&p[(size_t)row * 4]; // p0x p0y p1x p1y
  const size_t bb = (size_t)b * NPIX;
  f16* zr = z + (size_t)row * KP1;

#pragma unroll
  for (int gh = 0; gh < 2; ++gh) {
    const int g = gh * 4 + sub;        // pool group 0..7
    float acc[8];
#pragma unroll
    for (int ci = 0; ci < 8; ++ci) acc[ci] = -1e30f;
#pragma unroll
    for (int pt = 0; pt < 4; ++pt) {
      const int t = g * 4 + pt;
      const float lam = (float)t * (1.0f / 31.0f);
      const float px = pe.x * lam + pe.z * (1.f - lam) - 0.5f;
      const float py = pe.y * lam + pe.w * (1.f - lam) - 0.5f;
      const float px0 = fminf(fmaxf(floorf(px), 0.f), 127.f);
      const float py0 = fminf(fmaxf(floorf(py), 0.f), 127.f);
      const float px1 = fminf(px0 + 1.f, 127.f);
      const float py1 = fminf(py0 + 1.f, 127.f);
      const int ix0 = (int)px0, iy0 = (int)py0, ix1 = (int)px1, iy1 = (int)py1;
      const float w00 = (px1 - px) * (py1 - py);
      const float w10 = (px - px0) * (py1 - py);
      const float w01 = (px1 - px) * (py - py0);
      const float w11 = (px - px0) * (py - py0);

      const f16* r00 = x + (bb + ix0 * HW + iy0) * DLOI + cl * 8;
      const f16* r10 = x + (bb + ix1 * HW + iy0) * DLOI + cl * 8;
      const f16* r01 = x + (bb + ix0 * HW + iy1) * DLOI + cl * 8;
      const f16* r11 = x + (bb + ix1 * HW + iy1) * DLOI + cl * 8;
      f16x8 a  = *(const f16x8*)r00;
      f16x8 bq = *(const f16x8*)r10;
      f16x8 cq = *(const f16x8*)r01;
      f16x8 dq = *(const f16x8*)r11;
#pragma unroll
      for (int ci = 0; ci < 8; ++ci) {
        float m = w00 * (float)a[ci] + w10 * (float)bq[ci] +
                  w01 * (float)cq[ci] + w11 * (float)dq[ci];
        acc[ci] = fmaxf(acc[ci], m);
      }
    }
    f16x8 o;
#pragma unroll
    for (int ci = 0; ci < 8; ++ci) o[ci] = (f16)acc[ci];
    *(f16x8*)(zr + g * 128 + cl * 8) = o;
  }
  if (lane < 8) zr[1024 + lane] = (f16)feat[(size_t)row * 8 + lane];
  else if (lane < 36) *(unsigned int*)((char*)zr + 2064 + (lane - 8) * 4) = 0u;
}

// ---------------- weight transpose + fp16 + K-pad (+ optional k-permute for z layout)
__global__ __launch_bounds__(256) void wtrans_kernel(
    const float* __restrict__ W, f16* __restrict__ Wt, int K, int ldt, int permute) {
  __shared__ float t[32][33];
  const int tx = threadIdx.x & 31, ty = threadIdx.x >> 5;
#pragma unroll
  for (int i = 0; i < 4; ++i) {
    int kd = blockIdx.y * 32 + ty + i * 8;
    int ks = (permute && kd < 1024) ? ((kd & 127) * 8 + (kd >> 7)) : kd;
    int n = blockIdx.x * 32 + tx;
    t[ty + i * 8][tx] = (ks < K) ? W[(size_t)ks * DFC + n] : 0.f;
  }
  __syncthreads();
#pragma unroll
  for (int i = 0; i < 4; ++i) {
    int n = blockIdx.x * 32 + ty + i * 8;
    int k = blockIdx.y * 32 + tx;
    Wt[(size_t)n * ldt + k] = (f16)t[tx][ty + i * 8];
  }
}

// ---------------- fp16 MFMA GEMM: C[M][1024] = relu_f16(A[M][lda] @ Bt[1024][lda]^T + bias)
__global__ __launch_bounds__(256) void gemm_f16(
    const f16* __restrict__ A, const f16* __restrict__ Bt,
    const float* __restrict__ bias, f16* __restrict__ C,
    int M, int ksteps, int lda) {
  __shared__ f16 As[128 * 64];
  __shared__ f16 Bs[128 * 64];
  const int tid = threadIdx.x;
  const int l = tid & 63;
  const int w = tid >> 6;

  const int nwg = gridDim.x;            // 2504 (313 m-tiles x 8 n-tiles)
  const int s = (blockIdx.x & 7) * (nwg >> 3) + (blockIdx.x >> 3);
  const int m0 = (s >> 3) * 128;
  const int n0 = (s & 7) * 128;

  const int wr = (w >> 1) * 64, wc = (w & 1) * 64;
  const int srow = w * 8 + (l >> 3);
  const int slot = l & 7;

  f32x4 acc[4][4] = {};

  for (int kt = 0; kt < ksteps; ++kt) {
    const int kb = kt * 64;
    __syncthreads();
#pragma unroll
    for (int c = 0; c < 4; ++c) {
      int row = c * 32 + srow;
      int arow = m0 + row; if (arow >= M) arow = M - 1;
      const f16* g = A + (size_t)arow * lda + kb + ((slot ^ (row & 7)) * 8);
      __builtin_amdgcn_global_load_lds(
          (const __attribute__((address_space(1))) void*)g,
          (__attribute__((address_space(3))) void*)(As + row * 64 + slot * 8),
          16, 0, 0);
    }
#pragma unroll
    for (int c = 0; c < 4; ++c) {
      int row = c * 32 + srow;
      const f16* g = Bt + (size_t)(n0 + row) * lda + kb + ((slot ^ (row & 7)) * 8);
      __builtin_amdgcn_global_load_lds(
          (const __attribute__((address_space(1))) void*)g,
          (__attribute__((address_space(3))) void*)(Bs + row * 64 + slot * 8),
          16, 0, 0);
    }
    __syncthreads();

    const int lrow = l & 15;
    const int g4 = l >> 4;
#pragma unroll
    for (int kh = 0; kh < 2; ++kh) {
      f16x8 af[4], bf[4];
#pragma unroll
      for (int m = 0; m < 4; ++m) {
        int row = wr + m * 16 + lrow;
        int sl = (g4 + 4 * kh) ^ (row & 7);
        af[m] = *(const f16x8*)(As + row * 64 + sl * 8);
      }
#pragma unroll
      for (int n = 0; n < 4; ++n) {
        int row = wc + n * 16 + lrow;
        int sl = (g4 + 4 * kh) ^ (row & 7);
        bf[n] = *(const f16x8*)(Bs + row * 64 + sl * 8);
      }
#pragma unroll
      for (int m = 0; m < 4; ++m)
#pragma unroll
        for (int n = 0; n < 4; ++n)
          acc[m][n] = __builtin_amdgcn_mfma_f32_16x16x32_f16(af[m], bf[n], acc[m][n], 0, 0, 0);
    }
  }

  const int ocol0 = n0 + wc + (l & 15);
  const int orow0 = m0 + wr + (l >> 4) * 4;
#pragma unroll
  for (int m = 0; m < 4; ++m) {
#pragma unroll
    for (int r = 0; r < 4; ++r) {
      int orow = orow0 + m * 16 + r;
      if (orow >= M) continue;
      f16* crow = C + (size_t)orow * DFC;
#pragma unroll
      for (int n = 0; n < 4; ++n) {
        int col = ocol0 + n * 16;
        float v = acc[m][n][r] + bias[col];
        crow[col] = (f16)fmaxf(v, 0.f);
      }
    }
  }
}

// ---------------- fc3: out[m] = h2[m] . W3 + b3   (h2 fp16, W3 fp32)
__global__ __launch_bounds__(256) void fc3_kernel(
    const f16* __restrict__ H, const float* __restrict__ W3,
    const float* __restrict__ b3, float* __restrict__ out, int M) {
  const int lane = threadIdx.x & 63;
  const int w = threadIdx.x >> 6;
  const int row = blockIdx.x * 4 + w;
  if (row >= M) return;
  const f16* hr = H + (size_t)row * DFC;
  float s = 0.f;
#pragma unroll
  for (int k = 0; k < 2; ++k) {
    int j = (lane + k * 64) * 8;
    f16x8 hv = *(const f16x8*)&hr[j];
    float4 w0 = *(const float4*)&W3[j];
    float4 w1 = *(const float4*)&W3[j + 4];
    s += (float)hv[0] * w0.x + (float)hv[1] * w0.y +
         (float)hv[2] * w0.z + (float)hv[3] * w0.w +
         (float)hv[4] * w1.x + (float)hv[5] * w1.y +
         (float)hv[6] * w1.z + (float)hv[7] * w1.w;
  }
  for (int off = 32; off; off >>= 1) s += __shfl_xor(s, off);
  if (lane == 0) out[row] = s + b3[0];
}

extern "C" void kernel_launch(void* const* d_in, const int* in_sizes, int n_in,
                              void* d_out, int out_size, void* d_ws, size_t ws_size,
                              hipStream_t stream) {
  const float* feature = (const float*)d_in[0];
  const float* p       = (const float*)d_in[1];
  const float* feat    = (const float*)d_in[2];
  const float* W_fc1   = (const float*)d_in[3];
  const float* b_fc1   = (const float*)d_in[4];
  const float* W1      = (const float*)d_in[5];
  const float* b1      = (const float*)d_in[6];
  const float* W2      = (const float*)d_in[7];
  const float* b2      = (const float*)d_in[8];
  const float* W3      = (const float*)d_in[9];
  const float* b3      = (const float*)d_in[10];
  float* out = (float*)d_out;

  char* ws = (char*)d_ws;
  f16* x   = (f16*)(ws + 0);                    //  33,554,432 B
  f16* z   = (f16*)(ws + 33554432ULL);          //  87,040,000 B (40000x1088)
  f16* h1  = (f16*)(ws + 120594432ULL);         //  81,920,000 B (40000x1024)
  f16* W1t = (f16*)(ws + 202514432ULL);         //   2,228,224 B (1024x1088)
  f16* W2t = (f16*)(ws + 204742656ULL);         //   2,097,152 B (1024x1024)
  f16* h2  = z;  // z dead after gemm1

  hipLaunchKernelGGL(wtrans_kernel, dim3(32, 34), dim3(256), 0, stream,
                     W1, W1t, 1032, KP1, 1);
  hipLaunchKernelGGL(wtrans_kernel, dim3(32, 32), dim3(256), 0, stream,
                     W2, W2t, 1024, 1024, 0);
  hipLaunchKernelGGL(conv1x1_kernel, dim3(128, 8), dim3(256), 0, stream,
                     feature, W_fc1, b_fc1, x);
  hipLaunchKernelGGL(sample_kernel, dim3(10000), dim3(256), 0, stream,
                     x, p, feat, z);
  hipLaunchKernelGGL(gemm_f16, dim3(2504), dim3(256), 0, stream,
                     z, W1t, b1, h1, LROWS, KP1 / 64, KP1);
  hipLaunchKernelGGL(gemm_f16, dim3(2504), dim3(256), 0, stream,
                     h1, W2t, b2, h2, LROWS, DFC / 64, DFC);
  hipLaunchKernelGGL(fc3_kernel, dim3(10000), dim3(256), 0, stream,
                     h2, W3, b3, out, LROWS);
}